// Round 3
// baseline (517.893 us; speedup 1.0000x reference)
//
#include <hip/hip_runtime.h>

// ---------------------------------------------------------------------------
// cosine_seqNet: out[b,o] = conv_b[o] + (1/6) * sum_{d,w} conv_w[o,d,w] *
//                 P[b,d,w],  P[b,d,w] = sum_{t=0..5} x[b,t+w,d]*cos[b,t+w]
// (mean over the 6 conv output positions commuted into the conv sum)
// Shapes: B=256, S=10, D=4096, O=4096, W=5, K = D*W = 20480
// Dtypes: ALL inputs fp32, output fp32. GEMM runs in bf16 MFMA (error budget
// ~1.3e-3 vs 1.57e-2 threshold); P built fp32, stored bf16; conv_w converted
// fp32->bf16 during LDS staging (each element read from HBM exactly once).
// R2 bug fixed: W staging pointer now advances with k0 (was stuck at cols 0..31).
// ---------------------------------------------------------------------------

#define BDIM 256
#define SEQ 10
#define DDIM 4096
#define ODIM 4096
#define WDIM 5
#define GK 20480               // D*W
#define SPLITS 8
#define KSPLIT (GK / SPLITS)   // 2560
#define KITERS (KSPLIT / 32)   // 80

typedef __bf16 bf16x8 __attribute__((ext_vector_type(8)));
typedef float f32x4 __attribute__((ext_vector_type(4)));

__device__ __forceinline__ unsigned short f2bf(float f) {
    union { float f; unsigned v; } c; c.f = f;
    unsigned r = c.v + 0x7FFFu + ((c.v >> 16) & 1u);   // RNE
    return (unsigned short)(r >> 16);
}
__device__ __forceinline__ void async16(void* lds, const void* g) {
    __builtin_amdgcn_global_load_lds(
        (const __attribute__((address_space(1))) void*)g,
        (__attribute__((address_space(3))) void*)lds, 16, 0, 0);
}

// ---------------------------------------------------------------------------
// Kernel 1: cos[b,s] — one block per b
// ---------------------------------------------------------------------------
__global__ __launch_bounds__(256) void cos_kernel(const float* __restrict__ x,
                                                  float* __restrict__ cosv)
{
    const int b = blockIdx.x;
    const int tid = threadIdx.x;
    const float* xb = x + (size_t)b * SEQ * DDIM;
    float dot[SEQ], sq[SEQ];
#pragma unroll
    for (int s = 0; s < SEQ; ++s) { dot[s] = 0.f; sq[s] = 0.f; }

    for (int base = 0; base < DDIM; base += 1024) {
        const int d = base + tid * 4;
        const f32x4 c4 = *(const f32x4*)(xb + 6 * DDIM + d);
#pragma unroll
        for (int s = 0; s < SEQ; ++s) {
            const f32x4 v4 = *(const f32x4*)(xb + s * DDIM + d);
            dot[s] += v4[0] * c4[0] + v4[1] * c4[1] + v4[2] * c4[2] + v4[3] * c4[3];
            sq[s]  += v4[0] * v4[0] + v4[1] * v4[1] + v4[2] * v4[2] + v4[3] * v4[3];
        }
    }
#pragma unroll
    for (int s = 0; s < SEQ; ++s) {
#pragma unroll
        for (int off = 32; off > 0; off >>= 1) {
            dot[s] += __shfl_down(dot[s], off, 64);
            sq[s]  += __shfl_down(sq[s], off, 64);
        }
    }
    __shared__ float red[4][2 * SEQ];
    const int wave = tid >> 6, lane = tid & 63;
    if (lane == 0) {
#pragma unroll
        for (int s = 0; s < SEQ; ++s) { red[wave][s] = dot[s]; red[wave][SEQ + s] = sq[s]; }
    }
    __syncthreads();
    if (tid == 0) {
        const float S6 = red[0][SEQ + 6] + red[1][SEQ + 6] + red[2][SEQ + 6] + red[3][SEQ + 6];
        const float cn = fmaxf(sqrtf(S6), 1e-8f);
#pragma unroll
        for (int s = 0; s < SEQ; ++s) {
            const float Dv = red[0][s] + red[1][s] + red[2][s] + red[3][s];
            const float Sv = red[0][SEQ + s] + red[1][SEQ + s] + red[2][SEQ + s] + red[3][SEQ + s];
            cosv[b * SEQ + s] = Dv / (fmaxf(sqrtf(Sv), 1e-8f) * cn);
        }
    }
}

// ---------------------------------------------------------------------------
// Kernel 2: P[b, d*5+w] = bf16( sum_{t=0..5} x[b,t+w,d]*cos[b,t+w] )
// ---------------------------------------------------------------------------
__global__ __launch_bounds__(256) void build_p_kernel(const float* __restrict__ x,
                                                      const float* __restrict__ cosv,
                                                      unsigned short* __restrict__ P)
{
    const int b = blockIdx.x >> 2;
    const int chunk = blockIdx.x & 3;
    const int d0 = chunk * 1024 + threadIdx.x * 4;
    __shared__ float cs[SEQ];
    if (threadIdx.x < SEQ) cs[threadIdx.x] = cosv[b * SEQ + threadIdx.x];
    __syncthreads();

    const float* xb = x + (size_t)b * SEQ * DDIM + d0;
    float sc[SEQ][4];
#pragma unroll
    for (int s = 0; s < SEQ; ++s) {
        const f32x4 v4 = *(const f32x4*)(xb + s * DDIM);
        const float c = cs[s];
        sc[s][0] = v4[0] * c; sc[s][1] = v4[1] * c;
        sc[s][2] = v4[2] * c; sc[s][3] = v4[3] * c;
    }
    __attribute__((aligned(16))) unsigned short o[20];
#pragma unroll
    for (int w = 0; w < WDIM; ++w) {
#pragma unroll
        for (int j = 0; j < 4; ++j) {
            const float p = sc[w][j] + sc[w + 1][j] + sc[w + 2][j] +
                            sc[w + 3][j] + sc[w + 4][j] + sc[w + 5][j];
            o[j * WDIM + w] = f2bf(p);
        }
    }
    unsigned short* dst = P + ((size_t)b * DDIM + d0) * WDIM;
#pragma unroll
    for (int q = 0; q < 5; ++q)
        *(uint2*)(dst + q * 4) = *(const uint2*)(o + q * 4);
}

// ---------------------------------------------------------------------------
// Kernel 3: split-K GEMM.  Cpart[sp,m,n] = sum_k A[m,k]*W[n,k]
// A = P bf16 (256 x 20480), W = conv_w fp32 (4096 x 20480) cvt'd at staging.
// Tile: 256(m) x 64(n), BK=32. 4 waves; wave w owns m rows [w*64, w*64+64),
// 4x4 frags of 16x16x32 MFMA. grid = 64 n-tiles * 8 splits = 512 blocks.
// LDS quad-XOR swizzle (phys quad p holds logical quad p^(row&3)).
// ---------------------------------------------------------------------------
__global__ __launch_bounds__(256) void gemm_splitk_kernel(const unsigned short* __restrict__ A,
                                                          const float* __restrict__ W,
                                                          float* __restrict__ Cpart)
{
    const int bid = blockIdx.x;
    const int nt = bid & 63;
    const int sp = bid >> 6;
    const int tid = threadIdx.x;
    const int lane = tid & 63;
    const int wave = tid >> 6;

    __shared__ __align__(16) unsigned short lds_a[256 * 32];  // 16 KB
    __shared__ __align__(16) unsigned short lds_w[64 * 32];   //  4 KB

    f32x4 acc[4][4];
#pragma unroll
    for (int i = 0; i < 4; ++i)
#pragma unroll
        for (int j = 0; j < 4; ++j)
            acc[i][j] = (f32x4){0.f, 0.f, 0.f, 0.f};

    int k0 = sp * KSPLIT;

    // A staging: 4x async16/thread; phys dest q*4096B + tid*16B
    const int arow_lo = tid >> 2;
    const int apq = tid & 3;

    // W staging: thread -> row tid>>2 (0..63), logical quad tid&3
    const int wrow = tid >> 2;
    const int wcq = tid & 3;
    const float* wsrc = W + ((size_t)(nt * 64 + wrow)) * GK + wcq * 8;  // + k0 in loop!
    unsigned short* wdst = lds_w + wrow * 32 + ((wcq ^ (wrow & 3)) * 8);

    // fragment read geometry
    const int fm = lane & 15;             // m for A-frag, n for W-frag
    const int fg = lane >> 4;             // k-quad 0..3
    const unsigned short* ard[4];
    const unsigned short* wrd[4];
#pragma unroll
    for (int i = 0; i < 4; ++i) {
        const int ra = wave * 64 + i * 16 + fm;
        ard[i] = lds_a + ra * 32 + ((fg ^ (ra & 3)) * 8);
        const int rw = i * 16 + fm;
        wrd[i] = lds_w + rw * 32 + ((fg ^ (rw & 3)) * 8);
    }

    for (int it = 0; it < KITERS; ++it) {
        // A: global -> LDS direct, swizzled source column
#pragma unroll
        for (int q = 0; q < 4; ++q) {
            const int row = q * 64 + arow_lo;
            const char* src = (const char*)(A + (size_t)row * GK + k0) + ((apq ^ (row & 3)) * 16);
            async16((char*)lds_a + q * 4096 + tid * 16, src);
        }
        // W: fp32 global -> VGPR -> cvt bf16 -> LDS  (FIX: advance with k0)
        {
            const f32x4 w0 = *(const f32x4*)(wsrc + k0);
            const f32x4 w1 = *(const f32x4*)(wsrc + k0 + 4);
            bf16x8 wb;
#pragma unroll
            for (int e = 0; e < 4; ++e) { wb[e] = (__bf16)w0[e]; wb[4 + e] = (__bf16)w1[e]; }
            *(bf16x8*)wdst = wb;
        }
        __syncthreads();

        bf16x8 af[4], wf[4];
#pragma unroll
        for (int i = 0; i < 4; ++i) af[i] = *(const bf16x8*)ard[i];
#pragma unroll
        for (int j = 0; j < 4; ++j) wf[j] = *(const bf16x8*)wrd[j];
#pragma unroll
        for (int i = 0; i < 4; ++i)
#pragma unroll
            for (int j = 0; j < 4; ++j)
                acc[i][j] = __builtin_amdgcn_mfma_f32_16x16x32_bf16(af[i], wf[j], acc[i][j], 0, 0, 0);
        __syncthreads();
        k0 += 32;
    }

    // C/D layout: col(n) = lane&15, row(m) = (lane>>4)*4 + reg   [m89-verified]
    float* Cp = Cpart + (size_t)sp * (BDIM * ODIM);
    const int mbase = wave * 64 + fg * 4;
    const int nbase = nt * 64 + fm;
#pragma unroll
    for (int i = 0; i < 4; ++i)
#pragma unroll
        for (int j = 0; j < 4; ++j) {
            const int n = nbase + j * 16;
#pragma unroll
            for (int r = 0; r < 4; ++r) {
                const int m = mbase + i * 16 + r;
                Cp[(size_t)m * ODIM + n] = acc[i][j][r];
            }
        }
}

// ---------------------------------------------------------------------------
// Kernel 4: out[b,o] = sum_sp partial[sp,b,o] / 6 + conv_b[o]
// ---------------------------------------------------------------------------
__global__ __launch_bounds__(256) void reduce_kernel(const float* __restrict__ part,
                                                     const float* __restrict__ bias,
                                                     float* __restrict__ out)
{
    const int idx = (blockIdx.x * 256 + threadIdx.x) * 4;
    f32x4 s = (f32x4){0.f, 0.f, 0.f, 0.f};
#pragma unroll
    for (int sp = 0; sp < SPLITS; ++sp) {
        const f32x4 v = *(const f32x4*)(part + (size_t)sp * (BDIM * ODIM) + idx);
        s[0] += v[0]; s[1] += v[1]; s[2] += v[2]; s[3] += v[3];
    }
    const int n = idx & (ODIM - 1);
    const f32x4 b4 = *(const f32x4*)(bias + n);
    const float inv6 = 1.0f / 6.0f;
    f32x4 o;
#pragma unroll
    for (int e = 0; e < 4; ++e) o[e] = s[e] * inv6 + b4[e];
    *(f32x4*)(out + idx) = o;
}

// ---------------------------------------------------------------------------
extern "C" void kernel_launch(void* const* d_in, const int* in_sizes, int n_in,
                              void* d_out, int out_size, void* d_ws, size_t ws_size,
                              hipStream_t stream) {
    const float* x  = (const float*)d_in[0];   // fp32 (256,10,4096)
    const float* cw = (const float*)d_in[1];   // fp32 (4096,4096,5)
    const float* cb = (const float*)d_in[2];   // fp32 (4096,)
    float* out = (float*)d_out;                // fp32 (256,4096)

    char* ws = (char*)d_ws;
    float* cosv = (float*)ws;                                        // 10.2 KB
    unsigned short* P = (unsigned short*)(ws + 16384);               // 10.49 MB bf16
    float* parts = (float*)(ws + 16384 + (size_t)BDIM * GK * 2);     // 33.55 MB fp32

    hipLaunchKernelGGL(cos_kernel,         dim3(256),  dim3(256), 0, stream, x, cosv);
    hipLaunchKernelGGL(build_p_kernel,     dim3(1024), dim3(256), 0, stream, x, cosv, P);
    hipLaunchKernelGGL(gemm_splitk_kernel, dim3(512),  dim3(256), 0, stream, P, cw, parts);
    hipLaunchKernelGGL(reduce_kernel,      dim3(1024), dim3(256), 0, stream, parts, cb, out);
}